// Round 12
// baseline (219.547 us; speedup 1.0000x reference)
//
#include <hip/hip_runtime.h>
#include <hip/hip_bf16.h>
#include <math.h>

#define NROWS 32768   // N
#define DD 32         // D
#define PPH 16        // P
#define HH 256        // H
#define BB 65536      // B
#define TWO_LOG_C 1.8378770664093453f

typedef __attribute__((ext_vector_type(8))) __bf16 bf16x8;
typedef __attribute__((ext_vector_type(4))) float f32x4;
typedef unsigned int u32;

__device__ __forceinline__ float sigm_f(float x) { return 1.0f / (1.0f + __expf(-x)); }
__device__ __forceinline__ float tanh_f(float x) { return 1.0f - 2.0f / (1.0f + __expf(2.0f * x)); }

// async global->LDS, 16B per lane; LDS dest wave-uniform (HW adds lane*16)
__device__ __forceinline__ void gl_lds16(const __bf16* g, __bf16* l) {
    __builtin_amdgcn_global_load_lds(
        (const __attribute__((address_space(1))) u32*)g,
        (__attribute__((address_space(3))) u32*)l, 16, 0, 0);
}

// ---------------------------------------------------------------------------
// pre_kernel: unchanged from round 10 (this round isolates the gru edit).
//  blocks 0..4095   : prep (losses + G bf16) + Hb gather + h->h_out copy
//  blocks 4096..4239: weight transpose+cvt (96 Kt tiles, 48 Rt tiles)
// ---------------------------------------------------------------------------
__global__ __launch_bounds__(256) void pre_kernel(
    const float* __restrict__ h,          // [B,256]
    const float* __restrict__ p,          // [B,64]
    const float* __restrict__ X_obs,      // [N,32]
    const float* __restrict__ M_obs,      // [N,32]
    const int*   __restrict__ i_obs,      // [N]
    const float* __restrict__ w_prep,     // [D,4,P]
    const float* __restrict__ bias_prep,  // [D,P]
    const float* __restrict__ gk,         // [512,768]
    const float* __restrict__ grk,        // [256,768]
    float* __restrict__ losses,           // [N,32]
    __bf16* __restrict__ G,               // [N,512]
    __bf16* __restrict__ Hb,              // [N,256]
    __bf16* __restrict__ Kt,              // [768][512]
    __bf16* __restrict__ Rt,              // [768][256]
    float* __restrict__ h_out)            // [B,256]
{
    __shared__ float arena[4160];
    const int bid = blockIdx.x;
    const int tid = threadIdx.x;

    if (bid < 4096) {
        float (*w2)[33] = (float(*)[33])arena;
        float (*b2)[33] = (float(*)[33])(arena + 64 * 33);
        for (int i = tid; i < 2048; i += 256) w2[i & 63][i >> 6] = w_prep[i];
        for (int i = tid; i < 512; i += 256)  b2[i & 15][i >> 4] = bias_prep[i];
        __syncthreads();

        const int gid = bid * 256 + tid;
        const int n = gid >> 5;
        const int d = gid & 31;
        const int idx = i_obs[n];

        float mean   = p[idx * 64 + d];
        float logvar = p[idx * 64 + 32 + d];
        float x      = X_obs[gid];
        float m      = M_obs[gid];

        float inv_sigma = __expf(-0.5f * logvar);
        float err = (x - mean) * inv_sigma;
        losses[gid] = 0.5f * ((err * err + logvar + TWO_LOG_C) * m);

        #pragma unroll
        for (int q = 0; q < PPH; ++q) {
            float v = x      * w2[q][d]
                    + mean   * w2[16 + q][d]
                    + logvar * w2[32 + q][d]
                    + err    * w2[48 + q][d]
                    + b2[q][d];
            v = fmaxf(v, 0.0f) * m;
            G[(size_t)q * (NROWS * DD) + gid] = (__bf16)v;
        }

        const float* hsrc = h + (size_t)idx * 256 + d * 8;
        float4 a = ((const float4*)hsrc)[0];
        float4 b = ((const float4*)hsrc)[1];
        bf16x8 v8;
        v8[0] = (__bf16)a.x; v8[1] = (__bf16)a.y; v8[2] = (__bf16)a.z; v8[3] = (__bf16)a.w;
        v8[4] = (__bf16)b.x; v8[5] = (__bf16)b.y; v8[6] = (__bf16)b.z; v8[7] = (__bf16)b.w;
        *(bf16x8*)(Hb + (size_t)n * 256 + d * 8) = v8;

        const float4* hf4 = (const float4*)h;
        float4* of4 = (float4*)h_out;
        #pragma unroll
        for (int k2 = 0; k2 < 4; ++k2) {
            int i4 = gid + k2 * 1048576;
            of4[i4] = hf4[i4];
        }
    } else {
        float (*t)[65] = (float(*)[65])arena;
        int b = bid - 4096;
        const float* src; __bf16* dst; int K, k0, j0;
        if (b < 96) { src = gk;  dst = Kt; K = 512; k0 = (b & 7) * 64; j0 = (b >> 3) * 64; }
        else { b -= 96; src = grk; dst = Rt; K = 256; k0 = (b & 3) * 64; j0 = (b >> 2) * 64; }
        int tx = tid & 63, ty = tid >> 6;
        #pragma unroll
        for (int i = 0; i < 16; ++i) {
            int k = ty * 16 + i;
            t[k][tx] = src[(size_t)(k0 + k) * 768 + j0 + tx];
        }
        __syncthreads();
        #pragma unroll
        for (int i = 0; i < 16; ++i) {
            int j = ty * 16 + i;
            dst[(size_t)(j0 + j) * K + k0 + tx] = (__bf16)t[tx][j];
        }
    }
}

// ---------------------------------------------------------------------------
// gru: BK=64 restructure. 12 steps (8x G@Kt + 4x Hb@Rt), 48 MFMA/wave/step,
// 2-step prefetch (~1200cyc slack > HBM latency), half the barriers of r10.
// LDS: 2 x (A[128][64] + B[192][64]) bf16 = 81920 B exactly -> 2 blocks/CU.
// Row-major tiles; global source XOR-pre-swizzled (slot ^= row&7) so LDS
// stays linear for global_load_lds, each wave-load = 8 rows x full 128B line,
// and ds_read_b128 frags are 2-way aliased (free, m136).
// ---------------------------------------------------------------------------
#define A_BUF 8192    // elems per A buffer (128*64)
#define B_BUF 12288   // elems per B buffer (192*64)

__device__ __forceinline__ void stage(const __bf16* __restrict__ Asrc,
                                      const __bf16* __restrict__ Bsrc,
                                      int Kd, int i0, int j0, int koff,
                                      int wave, int lane,
                                      __bf16* dA, __bf16* dB) {
    const int rsub = lane >> 3;      // 8 rows per wave-load
    const int slot = lane & 7;       // 16B slot within 128B row
    #pragma unroll
    for (int s = 0; s < 10; ++s) {
        int u = wave * 10 + s;       // 0..39: 16 A-units then 24 B-units
        if (u < 16) {
            int ra = u * 8 + rsub;
            int xs = slot ^ (ra & 7);
            gl_lds16(Asrc + (size_t)(i0 + ra) * Kd + koff + xs * 8, dA + u * 512);
        } else {
            int v = u - 16;
            int rb = v * 8 + rsub;
            int xs = slot ^ (rb & 7);
            int mat = rb >> 6, jr = rb & 63;
            gl_lds16(Bsrc + (size_t)(mat * 256 + j0 + jr) * Kd + koff + xs * 8,
                     dB + v * 512);
        }
    }
}

__device__ __forceinline__ void compute(const __bf16* cA, const __bf16* cB,
    int kgrp, int lrow, int rw, int cw,
    f32x4 (&az)[4][2], f32x4 (&ar)[4][2], f32x4 (&ah)[4][2])
{
    #pragma unroll
    for (int kk = 0; kk < 2; ++kk) {
        const int sx = kk * 4 + kgrp;
        const int x8 = (sx ^ (lrow & 7)) * 8;
        bf16x8 af[4], bz[2], brf[2], bh[2];
        #pragma unroll
        for (int mt = 0; mt < 4; ++mt) {
            int ra = rw * 64 + mt * 16 + lrow;
            af[mt] = *(const bf16x8*)(cA + ra * 64 + x8);
        }
        #pragma unroll
        for (int jt = 0; jt < 2; ++jt) {
            int jr = cw * 32 + jt * 16 + lrow;
            bz[jt]  = *(const bf16x8*)(cB + (jr)       * 64 + x8);
            brf[jt] = *(const bf16x8*)(cB + (64 + jr)  * 64 + x8);
            bh[jt]  = *(const bf16x8*)(cB + (128 + jr) * 64 + x8);
        }
        __builtin_amdgcn_s_setprio(1);
        #pragma unroll
        for (int mt = 0; mt < 4; ++mt)
            #pragma unroll
            for (int jt = 0; jt < 2; ++jt) {
                az[mt][jt] = __builtin_amdgcn_mfma_f32_16x16x32_bf16(af[mt], bz[jt],  az[mt][jt], 0, 0, 0);
                ar[mt][jt] = __builtin_amdgcn_mfma_f32_16x16x32_bf16(af[mt], brf[jt], ar[mt][jt], 0, 0, 0);
                ah[mt][jt] = __builtin_amdgcn_mfma_f32_16x16x32_bf16(af[mt], bh[jt],  ah[mt][jt], 0, 0, 0);
            }
        __builtin_amdgcn_s_setprio(0);
    }
}

__global__ __launch_bounds__(256, 2) void gru_mfma_kernel(
    const __bf16* __restrict__ G,     // [N,512]
    const __bf16* __restrict__ Hb,    // [N,256]
    const float*  __restrict__ h,     // [B,256]
    const int*    __restrict__ i_obs,
    const __bf16* __restrict__ Kt,    // [768][512]
    const __bf16* __restrict__ Rt,    // [768][256]
    const float*  __restrict__ bi,
    const float*  __restrict__ brc,
    float* __restrict__ h_out)        // [B,256]
{
    __shared__ __bf16 ldsA[2 * A_BUF];   // 32 KB
    __shared__ __bf16 ldsB[2 * B_BUF];   // 48 KB  (total exactly 80 KB)

    const int tid  = threadIdx.x;
    const int lane = tid & 63;
    const int wave = tid >> 6;
    const int lrow = lane & 15;
    const int kgrp = lane >> 4;
    const int rw = wave >> 1;
    const int cw = wave & 1;

    // XCD-aware swizzle (1024 blocks, 8 XCDs; bijective since 1024%8==0)
    int bid = blockIdx.x;
    int swz = (bid & 7) * 128 + (bid >> 3);
    const int i0 = (swz >> 2) * 128;
    const int j0 = (swz & 3) * 64;

    f32x4 az[4][2], ar[4][2], axh[4][2], arh[4][2];
    const f32x4 zero4 = {0.f, 0.f, 0.f, 0.f};
    #pragma unroll
    for (int m = 0; m < 4; ++m)
        #pragma unroll
        for (int j = 0; j < 2; ++j) {
            az[m][j] = zero4; ar[m][j] = zero4; axh[m][j] = zero4; arh[m][j] = zero4;
        }

    // prologue: 2 steps in flight (20 loads/wave outstanding)
    stage(G, Kt, 512, i0, j0, 0,  wave, lane, ldsA,         ldsB);
    stage(G, Kt, 512, i0, j0, 64, wave, lane, ldsA + A_BUF, ldsB + B_BUF);

    #pragma unroll
    for (int t = 0; t < 8; ++t) {                      // phase 1: G @ Kt
        asm volatile("s_waitcnt vmcnt(10)" ::: "memory");
        __builtin_amdgcn_s_barrier();
        compute(ldsA + (t & 1) * A_BUF, ldsB + (t & 1) * B_BUF,
                kgrp, lrow, rw, cw, az, ar, axh);
        __builtin_amdgcn_s_barrier();
        int ns = t + 2;
        if (ns < 8)
            stage(G, Kt, 512, i0, j0, ns * 64, wave, lane,
                  ldsA + (ns & 1) * A_BUF, ldsB + (ns & 1) * B_BUF);
        else
            stage(Hb, Rt, 256, i0, j0, (ns - 8) * 64, wave, lane,
                  ldsA + (ns & 1) * A_BUF, ldsB + (ns & 1) * B_BUF);
    }
    #pragma unroll
    for (int tp = 0; tp < 4; ++tp) {                   // phase 2: Hb @ Rt
        if (tp < 3) { asm volatile("s_waitcnt vmcnt(10)" ::: "memory"); }
        else        { asm volatile("s_waitcnt vmcnt(0)"  ::: "memory"); }
        __builtin_amdgcn_s_barrier();
        compute(ldsA + (tp & 1) * A_BUF, ldsB + (tp & 1) * B_BUF,
                kgrp, lrow, rw, cw, az, ar, arh);
        __builtin_amdgcn_s_barrier();
        if (tp < 2)
            stage(Hb, Rt, 256, i0, j0, (tp + 2) * 64, wave, lane,
                  ldsA + (tp & 1) * A_BUF, ldsB + (tp & 1) * B_BUF);
    }

    // epilogue: gates + scatter (C/D: col=lane&15, row=(lane>>4)*4+reg)
    #pragma unroll
    for (int mt = 0; mt < 4; ++mt) {
        int rl0 = rw * 64 + mt * 16 + kgrp * 4;
        #pragma unroll
        for (int jt = 0; jt < 2; ++jt) {
            int j = j0 + cw * 32 + jt * 16 + lrow;
            float b_z  = bi[j]       + brc[j];
            float b_r  = bi[256 + j] + brc[256 + j];
            float b_xh = bi[512 + j];
            float b_rh = brc[512 + j];
            #pragma unroll
            for (int r = 0; r < 4; ++r) {
                int idx = i_obs[i0 + rl0 + r];
                size_t hoff = (size_t)idx * 256 + j;
                float z  = sigm_f(az[mt][jt][r] + b_z);
                float rg = sigm_f(ar[mt][jt][r] + b_r);
                float hh = tanh_f(axh[mt][jt][r] + b_xh + rg * (arh[mt][jt][r] + b_rh));
                float hp = h[hoff];
                h_out[hoff] = z * hp + (1.0f - z) * hh;
            }
        }
    }
}

// ---------------------------------------------------------------------------
extern "C" void kernel_launch(void* const* d_in, const int* in_sizes, int n_in,
                              void* d_out, int out_size, void* d_ws, size_t ws_size,
                              hipStream_t stream) {
    const float* h         = (const float*)d_in[0];
    const float* p         = (const float*)d_in[1];
    const float* X_obs     = (const float*)d_in[2];
    const float* M_obs     = (const float*)d_in[3];
    const int*   i_obs     = (const int*)  d_in[4];
    const float* w_prep    = (const float*)d_in[5];
    const float* bias_prep = (const float*)d_in[6];
    const float* gk        = (const float*)d_in[7];
    const float* grk       = (const float*)d_in[8];
    const float* gbi       = (const float*)d_in[9];
    const float* gbr       = (const float*)d_in[10];

    float* out    = (float*)d_out;
    float* h_out  = out;
    float* losses = out + (size_t)BB * HH;

    char* ws = (char*)d_ws;
    __bf16* G  = (__bf16*)ws;                          // 32 MiB
    __bf16* Kt = (__bf16*)(ws + 33554432);             // 768 KiB
    __bf16* Rt = (__bf16*)(ws + 34340864);             // 384 KiB
    __bf16* Hb = (__bf16*)(ws + 34734080);             // 16 MiB

    pre_kernel<<<4240, 256, 0, stream>>>(
        h, p, X_obs, M_obs, i_obs, w_prep, bias_prep, gk, grk,
        losses, G, Hb, Kt, Rt, h_out);

    gru_mfma_kernel<<<1024, 256, 0, stream>>>(
        G, Hb, h, i_obs, Kt, Rt, gbi, gbr, h_out);
}